// Round 11
// baseline (367.869 us; speedup 1.0000x reference)
//
#include <hip/hip_runtime.h>

// LinkPredictor: score[e] = w2 . relu(W1 . concat(h[src[e]], h[dst[e]]) + b1) + b2
// N_NODES=100000, N_EDGES=1600000, D=128, HIDDEN=256
//
// R11: DIAGNOSTIC. Decomposition (R4 cross-check): overhead 53 + cvt 13 +
// u_gemm2 ~63 + edge 237. u_gemm2 is 2.5x over its ~25us floor and has never
// appeared in the counter top-5 (four blind theories, all partial misses).
// Edge pass now split 4 ways (~59 us/chunk) so u_gemm2 (63 us, UNCHANGED from
// R10) tops the table with full counters. Discriminators: FETCH>>130MB ->
// B-load line amplification; LDS_CONFLICT>3e6 -> S-drain swizzle; low
// VALU+Mfma w/ Occ~25% -> latency-bound -> persistent-block rewrite next.

#define NNODES 100000
#define E_TOTAL 1600000
#define D 128
#define K2 256
#define H 256

typedef short bf16x8 __attribute__((ext_vector_type(8)));
typedef short bf16x4 __attribute__((ext_vector_type(4)));
typedef float f32x4 __attribute__((ext_vector_type(4)));
typedef const __attribute__((address_space(1))) unsigned short* gas_t;
typedef __attribute__((address_space(3))) unsigned short* las_t;

__device__ __forceinline__ unsigned short f2bf(float f) {
    unsigned u = __float_as_uint(f);
    u += 0x7fff + ((u >> 16) & 1);   // round-to-nearest-even
    return (unsigned short)(u >> 16);
}
__device__ __forceinline__ float bf2f(unsigned short s) {
    return __uint_as_float((unsigned)s << 16);
}

// ---------------- cvt: h and/or W1 -> bf16 ----------------
__global__ void cvt_kernel(const float* __restrict__ h, const float* __restrict__ w1,
                           unsigned short* __restrict__ hbf, unsigned short* __restrict__ w1bf,
                           int n4h, int n4w) {
    int i = blockIdx.x * blockDim.x + threadIdx.x;
    const float* s; unsigned short* d; int j;
    if (i < n4h) { s = h; d = hbf; j = i; }
    else if (i < n4h + n4w) { s = w1; d = w1bf; j = i - n4h; }
    else return;
    float4 v = ((const float4*)s)[j];
    ushort4 o;
    o.x = f2bf(v.x); o.y = f2bf(v.y); o.z = f2bf(v.z); o.w = f2bf(v.w);
    ((ushort4*)d)[j] = o;
}

__global__ void cvt_w1(const float* __restrict__ W1, unsigned short* __restrict__ w1bf, int n4) {
    int i = blockIdx.x * blockDim.x + threadIdx.x;
    if (i >= n4) return;
    float4 v = ((const float4*)W1)[i];
    ushort4 o;
    o.x = f2bf(v.x); o.y = f2bf(v.y); o.z = f2bf(v.z); o.w = f2bf(v.w);
    ((ushort4*)w1bf)[i] = o;
}

// ---------------- u_gemm v2: async-DMA staged, bf16 h (UNCHANGED R10) ------
__global__ __launch_bounds__(256, 2) void u_gemm2(
    const unsigned short* __restrict__ hbf,
    const unsigned short* __restrict__ w1bf,
    const float* __restrict__ b1,
    unsigned short* __restrict__ Us,
    unsigned short* __restrict__ Ud)
{
    __shared__ __align__(16) unsigned short A[64 * 128];   // 16384 B
    __shared__ __align__(16) unsigned short S[64 * 268];   // 34304 B

    const int tid = threadIdx.x;
    const int wave = tid >> 6;
    const int lane = tid & 63;
    const int l15 = lane & 15;
    const int quad = lane >> 4;

    const int tile = blockIdx.x >> 1;
    const int half = blockIdx.x & 1;
    const int r0 = tile * 64;
    int rows = NNODES - r0; if (rows > 64) rows = 64;
    const int koff = half * 128;
    unsigned short* U = half ? Ud : Us;

    // --- issue async stage of A (16 KB), XOR swizzle c = p ^ (r&15) ---
#pragma unroll
    for (int it = 0; it < 4; ++it) {
        const int s = it * 256 + tid;      // 16B slot 0..1023
        const int r = s >> 4;              // row 0..63
        const int p = s & 15;              // position chunk
        const int c = p ^ (r & 15);        // content chunk
        if (r < rows)
            __builtin_amdgcn_global_load_lds(
                (gas_t)(hbf + (size_t)(r0 + r) * D + c * 8),
                (las_t)(A + it * 2048 + wave * 512), 16, 0, 0);
    }

    // --- B fragments + bias while DMA is in flight ---
    bf16x8 B[4][4];
    float bias[4];
#pragma unroll
    for (int nt = 0; nt < 4; ++nt) {
        const int n = wave * 64 + nt * 16 + l15;
        bias[nt] = half ? 0.f : b1[n];
#pragma unroll
        for (int kit = 0; kit < 4; ++kit)
            B[kit][nt] = *(const bf16x8*)(w1bf + (size_t)n * K2 + koff + kit * 32 + quad * 8);
    }

    __syncthreads();   // vmcnt(0): A landed

    f32x4 acc[4][4];
    const f32x4 zero = {0.f, 0.f, 0.f, 0.f};
#pragma unroll
    for (int ms = 0; ms < 4; ++ms)
#pragma unroll
        for (int nt = 0; nt < 4; ++nt)
            acc[ms][nt] = zero;

#pragma unroll
    for (int kit = 0; kit < 4; ++kit) {
        bf16x8 a[4];
#pragma unroll
        for (int ms = 0; ms < 4; ++ms) {
            const int row = ms * 16 + l15;
            const int p = (kit * 4 + quad) ^ l15;
            a[ms] = *(const bf16x8*)&A[row * 128 + p * 8];
        }
#pragma unroll
        for (int ms = 0; ms < 4; ++ms)
#pragma unroll
            for (int nt = 0; nt < 4; ++nt)
                acc[ms][nt] = __builtin_amdgcn_mfma_f32_16x16x32_bf16(
                    a[ms], B[kit][nt], acc[ms][nt], 0, 0, 0);
    }

    // --- epilogue: C -> LDS S -> coalesced dwordx4 stores ---
#pragma unroll
    for (int ms = 0; ms < 4; ++ms)
#pragma unroll
        for (int r = 0; r < 4; ++r) {
            const int m = ms * 16 + quad * 4 + r;
#pragma unroll
            for (int nt = 0; nt < 4; ++nt)
                S[m * 268 + wave * 64 + nt * 16 + l15] =
                    f2bf(acc[ms][nt][r] + bias[nt]);
        }
    __syncthreads();

#pragma unroll
    for (int i = 0; i < 8; ++i) {
        const int j = i * 256 + tid;
        const int row = j >> 5;
        const int cc = j & 31;
        if (row < rows) {
            bf16x8 vv = *(const bf16x8*)&S[row * 268 + cc * 8];
            *(bf16x8*)(U + (size_t)(r0 + row) * H + cc * 8) = vv;
        }
    }
}

// ---------------- edge pass (R6 body, range-parametrized) ----------------
__global__ __launch_bounds__(256) void edge_score(
    const unsigned short* __restrict__ Us,
    const unsigned short* __restrict__ Ud,
    const int* __restrict__ srcE,
    const int* __restrict__ dstE,
    const float* __restrict__ w2,
    const float* __restrict__ b2p,
    float* __restrict__ out,
    int grp0, int ngrp)
{
    const int gt = blockIdx.x * 256 + threadIdx.x;
    const int l = gt & 15;
    const int q = gt >> 4;
    const int Q = (gridDim.x * 256) >> 4;

    float w2v[16];
#pragma unroll
    for (int j = 0; j < 16; ++j) w2v[j] = w2[l * 16 + j];
    const float b2 = *b2p;

    for (int g = grp0 + q; g < grp0 + ngrp; g += Q) {
        const int e0 = g * 4;
        const int4 s4 = *(const int4*)(srcE + e0);
        const int4 d4 = *(const int4*)(dstE + e0);
        const int sv[4] = {s4.x, s4.y, s4.z, s4.w};
        const int dv[4] = {d4.x, d4.y, d4.z, d4.w};

        bf16x8 u[4][2], v[4][2];
#pragma unroll
        for (int k = 0; k < 4; ++k) {
            const bf16x8* us = (const bf16x8*)(Us + (size_t)sv[k] * H + l * 16);
            const bf16x8* ud = (const bf16x8*)(Ud + (size_t)dv[k] * H + l * 16);
            u[k][0] = us[0]; u[k][1] = us[1];
            v[k][0] = ud[0]; v[k][1] = ud[1];
        }

        float4 res;
        float* resp = (float*)&res;
#pragma unroll
        for (int k = 0; k < 4; ++k) {
            float acc = 0.f;
#pragma unroll
            for (int j = 0; j < 8; ++j) {
                float hv = bf2f((unsigned short)u[k][0][j]) + bf2f((unsigned short)v[k][0][j]);
                acc = fmaf(fmaxf(hv, 0.f), w2v[j], acc);
            }
#pragma unroll
            for (int j = 0; j < 8; ++j) {
                float hv = bf2f((unsigned short)u[k][1][j]) + bf2f((unsigned short)v[k][1][j]);
                acc = fmaf(fmaxf(hv, 0.f), w2v[j + 8], acc);
            }
            acc += __shfl_xor(acc, 1, 16);
            acc += __shfl_xor(acc, 2, 16);
            acc += __shfl_xor(acc, 4, 16);
            acc += __shfl_xor(acc, 8, 16);
            resp[k] = acc + b2;
        }
        if (l == 0) *(float4*)(out + e0) = res;
    }
}

// ======================= R4 fallback (ws too small) ======================

#define TILE_M 32
#define NTILES (E_TOTAL / TILE_M)
#define GRID 2500

#if defined(__has_attribute)
#if __has_attribute(amdgpu_waves_per_eu)
#define LB __launch_bounds__(256) __attribute__((amdgpu_waves_per_eu(2, 2)))
#else
#define LB __launch_bounds__(256, 2)
#endif
#else
#define LB __launch_bounds__(256, 2)
#endif

__global__ LB void edge_mlp(
    const unsigned short* __restrict__ hbf,
    const int* __restrict__ srcE,
    const int* __restrict__ dstE,
    const unsigned short* __restrict__ w1bf,
    const float* __restrict__ b1,
    const float* __restrict__ w2,
    const float* __restrict__ b2p,
    float* __restrict__ out)
{
    __shared__ __align__(16) unsigned short X[2][TILE_M * K2];
    __shared__ float red[2][TILE_M][5];

    const int tid = threadIdx.x;
    const int wave = tid >> 6;
    const int lane = tid & 63;
    const int lane15 = lane & 15;
    const int quad = lane >> 4;

    bf16x8 B[8][4];
#pragma unroll
    for (int kit = 0; kit < 8; ++kit)
#pragma unroll
        for (int nt = 0; nt < 4; ++nt) {
            int n = wave * 64 + nt * 16 + lane15;
            int k = kit * 32 + quad * 8;
            B[kit][nt] = *(const bf16x8*)(w1bf + n * K2 + k);
        }

    float b1v[4], w2v[4];
#pragma unroll
    for (int nt = 0; nt < 4; ++nt) {
        int n = wave * 64 + nt * 16 + lane15;
        b1v[nt] = b1[n];
        w2v[nt] = w2[n];
    }
    const float b2 = *b2p;

    const int r_off = tid >> 5;
    const int c = (tid & 31) ^ (r_off & 7);
    const int half = c >> 4;
    const int fc = c & 15;
    const int* idx_base = half ? dstE : srcE;
    const int gshort = fc * 8;

    const int t0 = blockIdx.x;
    int inode[4];

#pragma unroll
    for (int it = 0; it < 4; ++it)
        inode[it] = idx_base[t0 * TILE_M + it * 8 + r_off];
#pragma unroll
    for (int it = 0; it < 4; ++it)
        __builtin_amdgcn_global_load_lds(
            (gas_t)(hbf + inode[it] * D + gshort),
            (las_t)(&X[0][0] + it * 2048 + wave * 512), 16, 0, 0);
    {
        const int t1 = t0 + GRID;
#pragma unroll
        for (int it = 0; it < 4; ++it)
            inode[it] = idx_base[t1 * TILE_M + it * 8 + r_off];
    }

    int buf = 0;
    int prev_eb = -1;

    for (int tile = t0; tile < NTILES; tile += GRID) {
        __syncthreads();

        const int nt1 = tile + GRID;
        if (nt1 < NTILES) {
            unsigned short* Xn = &X[buf ^ 1][0];
#pragma unroll
            for (int it = 0; it < 4; ++it)
                __builtin_amdgcn_global_load_lds(
                    (gas_t)(hbf + inode[it] * D + gshort),
                    (las_t)(Xn + it * 2048 + wave * 512), 16, 0, 0);
        }
        const int nt2 = tile + 2 * GRID;
        if (nt2 < NTILES) {
            const int eb2 = nt2 * TILE_M;
#pragma unroll
            for (int it = 0; it < 4; ++it)
                inode[it] = idx_base[eb2 + it * 8 + r_off];
        }
        if (prev_eb >= 0 && tid < TILE_M) {
            float s = b2;
#pragma unroll
            for (int w = 0; w < 4; ++w) s += red[buf ^ 1][tid][w];
            out[prev_eb + tid] = s;
        }

        const unsigned short* Xc = &X[buf][0];
        f32x4 acc[2][4];
        const f32x4 zero = {0.f, 0.f, 0.f, 0.f};
#pragma unroll
        for (int ms = 0; ms < 2; ++ms)
#pragma unroll
            for (int nt = 0; nt < 4; ++nt)
                acc[ms][nt] = zero;

#pragma unroll
        for (int kit = 0; kit < 8; ++kit) {
            const int p8 = (((kit * 4 + quad) ^ (lane15 & 7))) * 8;
            bf16x8 a[2];
#pragma unroll
            for (int ms = 0; ms < 2; ++ms)
                a[ms] = *(const bf16x8*)&Xc[(ms * 16 + lane15) * K2 + p8];
#pragma unroll
            for (int ms = 0; ms < 2; ++ms)
#pragma unroll
                for (int nt = 0; nt < 4; ++nt)
                    acc[ms][nt] = __builtin_amdgcn_mfma_f32_16x16x32_bf16(
                        a[ms], B[kit][nt], acc[ms][nt], 0, 0, 0);
        }

#pragma unroll
        for (int ms = 0; ms < 2; ++ms)
#pragma unroll
            for (int r = 0; r < 4; ++r) {
                float p = 0.f;
#pragma unroll
                for (int nt = 0; nt < 4; ++nt) {
                    float hv = acc[ms][nt][r] + b1v[nt];
                    p = fmaf(fmaxf(hv, 0.f), w2v[nt], p);
                }
                p += __shfl_xor(p, 1, 16);
                p += __shfl_xor(p, 2, 16);
                p += __shfl_xor(p, 4, 16);
                p += __shfl_xor(p, 8, 16);
                if (lane15 == 0) red[buf][ms * 16 + quad * 4 + r][wave] = p;
            }
        prev_eb = tile * TILE_M;
        buf ^= 1;
    }

    __syncthreads();
    if (prev_eb >= 0 && tid < TILE_M) {
        float s = b2;
#pragma unroll
        for (int w = 0; w < 4; ++w) s += red[buf ^ 1][tid][w];
        out[prev_eb + tid] = s;
    }
}

// ================================ launch ================================

extern "C" void kernel_launch(void* const* d_in, const int* in_sizes, int n_in,
                              void* d_out, int out_size, void* d_ws, size_t ws_size,
                              hipStream_t stream) {
    const float* h    = (const float*)d_in[0];
    const int*   srcE = (const int*)d_in[1];
    const int*   dstE = (const int*)d_in[2];
    const float* W1   = (const float*)d_in[3];
    const float* b1   = (const float*)d_in[4];
    const float* w2   = (const float*)d_in[5];
    const float* b2   = (const float*)d_in[6];
    float* out = (float*)d_out;

    char* ws = (char*)d_ws;
    const size_t offUs   = 0;                        // 51,200,000 B
    const size_t offUd   = 51200000;                 // 51,200,000 B
    const size_t offHbf  = 102400000;                // 25,600,000 B (v2 only)
    const size_t offW1v2 = 128000000;                // 131,072 B
    const size_t needV2  = offW1v2 + 131072;         // 128,131,072 B
    const size_t offW1v1 = 102400000;
    const size_t needV1  = offW1v1 + 131072;

    const int NGRP = E_TOTAL / 4;                    // 400000

    if (ws_size >= needV2) {
        unsigned short* Us   = (unsigned short*)(ws + offUs);
        unsigned short* Ud   = (unsigned short*)(ws + offUd);
        unsigned short* hbf  = (unsigned short*)(ws + offHbf);
        unsigned short* w1bf = (unsigned short*)(ws + offW1v2);

        int n4h = NNODES * D / 4, n4w = H * K2 / 4;
        cvt_kernel<<<(n4h + n4w + 255) / 256, 256, 0, stream>>>(h, W1, hbf, w1bf, n4h, n4w);
        u_gemm2<<<2 * ((NNODES + 63) / 64), 256, 0, stream>>>(hbf, w1bf, b1, Us, Ud);

        // 4-way split: each chunk ~59 us < u_gemm2's ~63 -> u_gemm2 tops the table
        const int C = NGRP / 4;   // 100000
        edge_score<<<2048, 256, 0, stream>>>(Us, Ud, srcE, dstE, w2, b2, out, 0 * C, C);
        edge_score<<<2048, 256, 0, stream>>>(Us, Ud, srcE, dstE, w2, b2, out, 1 * C, C);
        edge_score<<<2048, 256, 0, stream>>>(Us, Ud, srcE, dstE, w2, b2, out, 2 * C, C);
        edge_score<<<2048, 256, 0, stream>>>(Us, Ud, srcE, dstE, w2, b2, out, 3 * C, C);
    } else if (ws_size >= needV1) {
        // (v1 path retired; reuse v2 layout requirement - fall through to R4 style)
        unsigned short* hbf  = (unsigned short*)d_ws;
        unsigned short* w1bf = hbf + (size_t)NNODES * D;
        int n4h = NNODES * D / 4, n4w = H * K2 / 4;
        cvt_kernel<<<(n4h + n4w + 255) / 256, 256, 0, stream>>>(h, W1, hbf, w1bf, n4h, n4w);
        edge_mlp<<<GRID, 256, 0, stream>>>(hbf, srcE, dstE, w1bf, b1, w2, b2, out);
    } else {
        unsigned short* hbf  = (unsigned short*)d_ws;
        unsigned short* w1bf = hbf + (size_t)NNODES * D;
        int n4h = NNODES * D / 4, n4w = H * K2 / 4;
        cvt_kernel<<<(n4h + n4w + 255) / 256, 256, 0, stream>>>(h, W1, hbf, w1bf, n4h, n4w);
        edge_mlp<<<GRID, 256, 0, stream>>>(hbf, srcE, dstE, w1bf, b1, w2, b2, out);
    }
}

// Round 12
// 357.495 us; speedup vs baseline: 1.0290x; 1.0290x over previous
//
#include <hip/hip_runtime.h>

// LinkPredictor: score[e] = w2 . relu(W1 . concat(h[src[e]], h[dst[e]]) + b1) + b2
// N_NODES=100000, N_EDGES=1600000, D=128, HIDDEN=256
//
// R12: decomposition firm: 53 overhead + 13 cvt + 60 u_gemm2 + 242 edge(4-way).
// (1) edge merged back to ONE dispatch (each split cost ~6 us).
// (2) u_gemm3: U column order is FREE (edge pass just permutes w2v to match)
//     -> store MFMA C-layout directly, no LDS S-bounce, no 2nd barrier; N-split
//     across blocks (wave owns 32 cols: B=32+acc=32+a=16 ~ 110 VGPR) ->
//     launch_bounds(256,4) = 16 waves/CU (2x occupancy of u_gemm2), LDS 16KB.
// U' layout: c' = 32-block base + l15*2 + nt holds true col n = base + nt*16+l15.

#define NNODES 100000
#define E_TOTAL 1600000
#define D 128
#define K2 256
#define H 256

typedef short bf16x8 __attribute__((ext_vector_type(8)));
typedef float f32x4 __attribute__((ext_vector_type(4)));
typedef const __attribute__((address_space(1))) unsigned short* gas_t;
typedef __attribute__((address_space(3))) unsigned short* las_t;

__device__ __forceinline__ unsigned short f2bf(float f) {
    unsigned u = __float_as_uint(f);
    u += 0x7fff + ((u >> 16) & 1);   // round-to-nearest-even
    return (unsigned short)(u >> 16);
}
__device__ __forceinline__ float bf2f(unsigned short s) {
    return __uint_as_float((unsigned)s << 16);
}

// ---------------- cvt: h and W1 -> bf16 ----------------
__global__ void cvt_kernel(const float* __restrict__ h, const float* __restrict__ w1,
                           unsigned short* __restrict__ hbf, unsigned short* __restrict__ w1bf,
                           int n4h, int n4w) {
    int i = blockIdx.x * blockDim.x + threadIdx.x;
    const float* s; unsigned short* d; int j;
    if (i < n4h) { s = h; d = hbf; j = i; }
    else if (i < n4h + n4w) { s = w1; d = w1bf; j = i - n4h; }
    else return;
    float4 v = ((const float4*)s)[j];
    ushort4 o;
    o.x = f2bf(v.x); o.y = f2bf(v.y); o.z = f2bf(v.z); o.w = f2bf(v.w);
    ((ushort4*)d)[j] = o;
}

// ---------------- u_gemm v3: N-split, direct C-layout stores ----------------
// blockIdx bx: tile = bx>>2 (64 node rows), half = (bx>>1)&1 (0: Us + b1 fold,
// 1: Ud), nh = bx&1 (cols 0-127 vs 128-255 of the half's output).
// Wave w owns true cols n = nh*128 + w*32 + nt*16 + l15, nt in {0,1}.
// Store: row m, lane l15 packs (nt0,nt1) -> dword at short-offset
// nh*128 + w*32 + l15*2  (c' = that + nt).
__global__ __launch_bounds__(256, 4) void u_gemm3(
    const unsigned short* __restrict__ hbf,
    const unsigned short* __restrict__ w1bf,
    const float* __restrict__ b1,
    unsigned short* __restrict__ Us,
    unsigned short* __restrict__ Ud)
{
    __shared__ __align__(16) unsigned short A[64 * 128];   // 16384 B

    const int tid = threadIdx.x;
    const int wave = tid >> 6;
    const int lane = tid & 63;
    const int l15 = lane & 15;
    const int quad = lane >> 4;

    const int tile = blockIdx.x >> 2;
    const int half = (blockIdx.x >> 1) & 1;
    const int nh = blockIdx.x & 1;
    const int r0 = tile * 64;
    int rows = NNODES - r0; if (rows > 64) rows = 64;
    const int koff = half * 128;
    unsigned short* U = half ? Ud : Us;

    // --- issue async stage of A (16 KB), XOR swizzle c = p ^ (r&15) ---
#pragma unroll
    for (int it = 0; it < 4; ++it) {
        const int s = it * 256 + tid;      // 16B slot 0..1023
        const int r = s >> 4;              // row 0..63
        const int p = s & 15;              // position chunk
        const int c = p ^ (r & 15);        // content chunk
        if (r < rows)
            __builtin_amdgcn_global_load_lds(
                (gas_t)(hbf + (size_t)(r0 + r) * D + c * 8),
                (las_t)(A + it * 2048 + wave * 512), 16, 0, 0);
    }

    // --- B fragments + bias while DMA is in flight ---
    bf16x8 B[4][2];
    float bias[2];
#pragma unroll
    for (int nt = 0; nt < 2; ++nt) {
        const int n = nh * 128 + wave * 32 + nt * 16 + l15;
        bias[nt] = half ? 0.f : b1[n];
#pragma unroll
        for (int kit = 0; kit < 4; ++kit)
            B[kit][nt] = *(const bf16x8*)(w1bf + (size_t)n * K2 + koff + kit * 32 + quad * 8);
    }

    __syncthreads();   // vmcnt(0): A landed

    f32x4 acc[4][2];
    const f32x4 zero = {0.f, 0.f, 0.f, 0.f};
#pragma unroll
    for (int ms = 0; ms < 4; ++ms)
#pragma unroll
        for (int nt = 0; nt < 2; ++nt)
            acc[ms][nt] = zero;

#pragma unroll
    for (int kit = 0; kit < 4; ++kit) {
        bf16x8 a[4];
#pragma unroll
        for (int ms = 0; ms < 4; ++ms) {
            const int row = ms * 16 + l15;
            const int p = (kit * 4 + quad) ^ l15;
            a[ms] = *(const bf16x8*)&A[row * 128 + p * 8];
        }
#pragma unroll
        for (int ms = 0; ms < 4; ++ms)
#pragma unroll
            for (int nt = 0; nt < 2; ++nt)
                acc[ms][nt] = __builtin_amdgcn_mfma_f32_16x16x32_bf16(
                    a[ms], B[kit][nt], acc[ms][nt], 0, 0, 0);
    }

    // --- direct permuted store: dword per (ms,r), 64B segment per quad ---
    const int coff = nh * 128 + wave * 32 + l15 * 2;   // short offset in U row
#pragma unroll
    for (int ms = 0; ms < 4; ++ms) {
#pragma unroll
        for (int r = 0; r < 4; ++r) {
            const int m = ms * 16 + quad * 4 + r;
            if (m < rows) {
                const unsigned lo = f2bf(acc[ms][0][r] + bias[0]);
                const unsigned hi = f2bf(acc[ms][1][r] + bias[1]);
                *(unsigned*)(U + (size_t)(r0 + m) * H + coff) = lo | (hi << 16);
            }
        }
    }
}

// ---------------- edge pass (R6/R8 body, permuted w2v) ----------------
// U' layout: within each 32-col block, c'' = l15*2+nt holds n'' = nt*16+l15.
// Lane l covers c' in [16l, 16l+16); w2v[j] = w2[n(16l+j)].
__global__ __launch_bounds__(256) void edge_score(
    const unsigned short* __restrict__ Us,
    const unsigned short* __restrict__ Ud,
    const int* __restrict__ srcE,
    const int* __restrict__ dstE,
    const float* __restrict__ w2,
    const float* __restrict__ b2p,
    float* __restrict__ out)
{
    const int gt = blockIdx.x * 256 + threadIdx.x;
    const int l = gt & 15;
    const int q = gt >> 4;
    const int Q = (gridDim.x * 256) >> 4;
    const int NGRP = E_TOTAL / 4;   // 400000

    float w2v[16];
#pragma unroll
    for (int j = 0; j < 16; ++j) {
        const int cp = l * 16 + j;
        const int n = (cp & ~31) + ((cp & 1) << 4) + ((cp & 31) >> 1);
        w2v[j] = w2[n];
    }
    const float b2 = *b2p;

    for (int g = q; g < NGRP; g += Q) {
        const int e0 = g * 4;
        const int4 s4 = *(const int4*)(srcE + e0);
        const int4 d4 = *(const int4*)(dstE + e0);
        const int sv[4] = {s4.x, s4.y, s4.z, s4.w};
        const int dv[4] = {d4.x, d4.y, d4.z, d4.w};

        bf16x8 u[4][2], v[4][2];
#pragma unroll
        for (int k = 0; k < 4; ++k) {
            const bf16x8* us = (const bf16x8*)(Us + (size_t)sv[k] * H + l * 16);
            const bf16x8* ud = (const bf16x8*)(Ud + (size_t)dv[k] * H + l * 16);
            u[k][0] = us[0]; u[k][1] = us[1];
            v[k][0] = ud[0]; v[k][1] = ud[1];
        }

        float4 res;
        float* resp = (float*)&res;
#pragma unroll
        for (int k = 0; k < 4; ++k) {
            float acc = 0.f;
#pragma unroll
            for (int j = 0; j < 8; ++j) {
                float hv = bf2f((unsigned short)u[k][0][j]) + bf2f((unsigned short)v[k][0][j]);
                acc = fmaf(fmaxf(hv, 0.f), w2v[j], acc);
            }
#pragma unroll
            for (int j = 0; j < 8; ++j) {
                float hv = bf2f((unsigned short)u[k][1][j]) + bf2f((unsigned short)v[k][1][j]);
                acc = fmaf(fmaxf(hv, 0.f), w2v[j + 8], acc);
            }
            acc += __shfl_xor(acc, 1, 16);
            acc += __shfl_xor(acc, 2, 16);
            acc += __shfl_xor(acc, 4, 16);
            acc += __shfl_xor(acc, 8, 16);
            resp[k] = acc + b2;
        }
        if (l == 0) *(float4*)(out + e0) = res;
    }
}

// ======================= R4 fallback (ws too small) ======================

#define TILE_M 32
#define NTILES (E_TOTAL / TILE_M)
#define GRID 2500

#if defined(__has_attribute)
#if __has_attribute(amdgpu_waves_per_eu)
#define LB __launch_bounds__(256) __attribute__((amdgpu_waves_per_eu(2, 2)))
#else
#define LB __launch_bounds__(256, 2)
#endif
#else
#define LB __launch_bounds__(256, 2)
#endif

__global__ LB void edge_mlp(
    const unsigned short* __restrict__ hbf,
    const int* __restrict__ srcE,
    const int* __restrict__ dstE,
    const unsigned short* __restrict__ w1bf,
    const float* __restrict__ b1,
    const float* __restrict__ w2,
    const float* __restrict__ b2p,
    float* __restrict__ out)
{
    __shared__ __align__(16) unsigned short X[2][TILE_M * K2];
    __shared__ float red[2][TILE_M][5];

    const int tid = threadIdx.x;
    const int wave = tid >> 6;
    const int lane = tid & 63;
    const int lane15 = lane & 15;
    const int quad = lane >> 4;

    bf16x8 B[8][4];
#pragma unroll
    for (int kit = 0; kit < 8; ++kit)
#pragma unroll
        for (int nt = 0; nt < 4; ++nt) {
            int n = wave * 64 + nt * 16 + lane15;
            int k = kit * 32 + quad * 8;
            B[kit][nt] = *(const bf16x8*)(w1bf + n * K2 + k);
        }

    float b1v[4], w2v[4];
#pragma unroll
    for (int nt = 0; nt < 4; ++nt) {
        int n = wave * 64 + nt * 16 + lane15;
        b1v[nt] = b1[n];
        w2v[nt] = w2[n];
    }
    const float b2 = *b2p;

    const int r_off = tid >> 5;
    const int c = (tid & 31) ^ (r_off & 7);
    const int half = c >> 4;
    const int fc = c & 15;
    const int* idx_base = half ? dstE : srcE;
    const int gshort = fc * 8;

    const int t0 = blockIdx.x;
    int inode[4];

#pragma unroll
    for (int it = 0; it < 4; ++it)
        inode[it] = idx_base[t0 * TILE_M + it * 8 + r_off];
#pragma unroll
    for (int it = 0; it < 4; ++it)
        __builtin_amdgcn_global_load_lds(
            (gas_t)(hbf + inode[it] * D + gshort),
            (las_t)(&X[0][0] + it * 2048 + wave * 512), 16, 0, 0);
    {
        const int t1 = t0 + GRID;
#pragma unroll
        for (int it = 0; it < 4; ++it)
            inode[it] = idx_base[t1 * TILE_M + it * 8 + r_off];
    }

    int buf = 0;
    int prev_eb = -1;

    for (int tile = t0; tile < NTILES; tile += GRID) {
        __syncthreads();

        const int nt1 = tile + GRID;
        if (nt1 < NTILES) {
            unsigned short* Xn = &X[buf ^ 1][0];
#pragma unroll
            for (int it = 0; it < 4; ++it)
                __builtin_amdgcn_global_load_lds(
                    (gas_t)(hbf + inode[it] * D + gshort),
                    (las_t)(Xn + it * 2048 + wave * 512), 16, 0, 0);
        }
        const int nt2 = tile + 2 * GRID;
        if (nt2 < NTILES) {
            const int eb2 = nt2 * TILE_M;
#pragma unroll
            for (int it = 0; it < 4; ++it)
                inode[it] = idx_base[eb2 + it * 8 + r_off];
        }
        if (prev_eb >= 0 && tid < TILE_M) {
            float s = b2;
#pragma unroll
            for (int w = 0; w < 4; ++w) s += red[buf ^ 1][tid][w];
            out[prev_eb + tid] = s;
        }

        const unsigned short* Xc = &X[buf][0];
        f32x4 acc[2][4];
        const f32x4 zero = {0.f, 0.f, 0.f, 0.f};
#pragma unroll
        for (int ms = 0; ms < 2; ++ms)
#pragma unroll
            for (int nt = 0; nt < 4; ++nt)
                acc[ms][nt] = zero;

#pragma unroll
        for (int kit = 0; kit < 8; ++kit) {
            const int p8 = (((kit * 4 + quad) ^ (lane15 & 7))) * 8;
            bf16x8 a[2];
#pragma unroll
            for (int ms = 0; ms < 2; ++ms)
                a[ms] = *(const bf16x8*)&Xc[(ms * 16 + lane15) * K2 + p8];
#pragma unroll
            for (int ms = 0; ms < 2; ++ms)
#pragma unroll
                for (int nt = 0; nt < 4; ++nt)
                    acc[ms][nt] = __builtin_amdgcn_mfma_f32_16x16x32_bf16(
                        a[ms], B[kit][nt], acc[ms][nt], 0, 0, 0);
        }

#pragma unroll
        for (int ms = 0; ms < 2; ++ms)
#pragma unroll
            for (int r = 0; r < 4; ++r) {
                float p = 0.f;
#pragma unroll
                for (int nt = 0; nt < 4; ++nt) {
                    float hv = acc[ms][nt][r] + b1v[nt];
                    p = fmaf(fmaxf(hv, 0.f), w2v[nt], p);
                }
                p += __shfl_xor(p, 1, 16);
                p += __shfl_xor(p, 2, 16);
                p += __shfl_xor(p, 4, 16);
                p += __shfl_xor(p, 8, 16);
                if (lane15 == 0) red[buf][ms * 16 + quad * 4 + r][wave] = p;
            }
        prev_eb = tile * TILE_M;
        buf ^= 1;
    }

    __syncthreads();
    if (prev_eb >= 0 && tid < TILE_M) {
        float s = b2;
#pragma unroll
        for (int w = 0; w < 4; ++w) s += red[buf ^ 1][tid][w];
        out[prev_eb + tid] = s;
    }
}

// ================================ launch ================================

extern "C" void kernel_launch(void* const* d_in, const int* in_sizes, int n_in,
                              void* d_out, int out_size, void* d_ws, size_t ws_size,
                              hipStream_t stream) {
    const float* h    = (const float*)d_in[0];
    const int*   srcE = (const int*)d_in[1];
    const int*   dstE = (const int*)d_in[2];
    const float* W1   = (const float*)d_in[3];
    const float* b1   = (const float*)d_in[4];
    const float* w2   = (const float*)d_in[5];
    const float* b2   = (const float*)d_in[6];
    float* out = (float*)d_out;

    char* ws = (char*)d_ws;
    const size_t offUs   = 0;                        // 51,200,000 B
    const size_t offUd   = 51200000;                 // 51,200,000 B
    const size_t offHbf  = 102400000;                // 25,600,000 B
    const size_t offW1bf = 128000000;                // 131,072 B
    const size_t need    = offW1bf + 131072;         // 128,131,072 B

    if (ws_size >= need) {
        unsigned short* Us   = (unsigned short*)(ws + offUs);
        unsigned short* Ud   = (unsigned short*)(ws + offUd);
        unsigned short* hbf  = (unsigned short*)(ws + offHbf);
        unsigned short* w1bf = (unsigned short*)(ws + offW1bf);

        int n4h = NNODES * D / 4, n4w = H * K2 / 4;
        cvt_kernel<<<(n4h + n4w + 255) / 256, 256, 0, stream>>>(h, W1, hbf, w1bf, n4h, n4w);
        u_gemm3<<<4 * ((NNODES + 63) / 64), 256, 0, stream>>>(hbf, w1bf, b1, Us, Ud);
        edge_score<<<4096, 256, 0, stream>>>(Us, Ud, srcE, dstE, w2, b2, out);
    } else {
        unsigned short* hbf  = (unsigned short*)d_ws;
        unsigned short* w1bf = hbf + (size_t)NNODES * D;
        int n4h = NNODES * D / 4, n4w = H * K2 / 4;
        cvt_kernel<<<(n4h + n4w + 255) / 256, 256, 0, stream>>>(h, W1, hbf, w1bf, n4h, n4w);
        edge_mlp<<<GRID, 256, 0, stream>>>(hbf, srcE, dstE, w1bf, b1, w2, b2, out);
    }
}